// Round 5
// baseline (171.328 us; speedup 1.0000x reference)
//
#include <hip/hip_runtime.h>

typedef unsigned short u16;
typedef unsigned int   u32;
typedef __bf16 bf16x8 __attribute__((ext_vector_type(8)));
typedef float  f32x4  __attribute__((ext_vector_type(4)));
typedef float  f32x16 __attribute__((ext_vector_type(16)));
typedef u32    u32x4  __attribute__((ext_vector_type(4)));
typedef u16    u16x8  __attribute__((ext_vector_type(8)));

#define DEVINL __device__ __forceinline__

DEVINL void glds16(const void* g, void* l) {
  __builtin_amdgcn_global_load_lds((const __attribute__((address_space(1))) u32*)g,
                                   (__attribute__((address_space(3))) u32*)l, 16, 0, 0);
}

DEVINL u16 f2bf(float f) {  // RNE float->bf16 (finite inputs)
  u32 u = __builtin_bit_cast(u32, f);
  u32 r = u + 0x7fffu + ((u >> 16) & 1u);
  return (u16)(r >> 16);
}

// ---------------- weight cast+transpose: W[K][N] f32 -> Wt[N][K] bf16 ----------------
// Total elements: 65536 + 131072 + 65536 = 262144 = 1024 blocks x 256. GRID MUST BE 1024.
__global__ __launch_bounds__(256) void castw_k(const float* __restrict__ Wq,
                                               const float* __restrict__ Wkv,
                                               const float* __restrict__ Wo,
                                               u16* __restrict__ WqT, u16* __restrict__ WkvT,
                                               u16* __restrict__ WoT) {
  int i = blockIdx.x * 256 + threadIdx.x;
  if (i < 65536) {              // Wq 256x256
    int n = i >> 8, k = i & 255;
    WqT[i] = f2bf(Wq[k * 256 + n]);
  } else if (i < 196608) {      // Wkv 256x512
    int j = i - 65536; int n = j >> 8, k = j & 255;
    WkvT[j] = f2bf(Wkv[k * 512 + n]);
  } else {                      // Wo 256x256
    int j = i - 196608; int n = j >> 8, k = j & 255;
    WoT[j] = f2bf(Wo[k * 256 + n]);
  }
}

// ---------------- GEMM body: C[M][N] = A[M][256] * Bt[N][256]^T + bias ----------------
// EPI 0: f32 out (+bias).  EPI 1: bf16 out, (acc+bias)*scale.  EPI 2: kv split per-head K/V.
// ASRC 0: bf16 A via global_load_lds.  1: reg-stage f32 A with cvt.
// ASRC 2: A = sum of 4 attn O-partials (f32) normalized by summed den, cast to bf16.
// XCDSWZ: chunk blocks per XCD so nt-siblings of an A-panel share L2 (nblk%8==0).
template<int EPI, int ASRC, bool XCDSWZ>
DEVINL void gemm_body(const void* __restrict__ Ap, const u16* __restrict__ Bt,
                      const float* __restrict__ bias, void* __restrict__ Cp,
                      void* __restrict__ C2p, const float* __restrict__ Dp,
                      u16* As, u16* Bs, int N, int nmt, float scale, int bid, int nblk) {
  const int K = 256;
  int tid = threadIdx.x, lane = tid & 63, w = tid >> 6;
  int g = lane >> 4, ln15 = lane & 15;
  int mt, nt;
  if (XCDSWZ) {
    int u = (bid & 7) * (nblk >> 3) + (bid >> 3);  // contiguous chunk per XCD
    mt = u >> 2; nt = u & 3;                       // XCD covers all nt of its mt range
  } else {
    mt = bid % nmt; nt = bid / nmt;
  }
  int arow0 = mt * 128, bcol0 = nt * 128;
  int wr = w >> 1, wc = w & 1;
  f32x4 acc[4][4] = {};

  for (int kt = 0; kt < 4; ++kt) {
    if (kt) __syncthreads();
    // ---- stage A tile [128][64] bf16, XOR-swizzled 16B chunks ----
    if (ASRC == 1) {
      const float* A = (const float*)Ap;
      #pragma unroll
      for (int i = 0; i < 4; ++i) {
        int c = i * 256 + tid; int row = c >> 3, k8 = c & 7;
        const float* src = A + (size_t)(arow0 + row) * K + kt * 64 + k8 * 8;
        f32x4 f0 = *(const f32x4*)src, f1 = *(const f32x4*)(src + 4);
        u16x8 hh;
        hh[0]=f2bf(f0[0]); hh[1]=f2bf(f0[1]); hh[2]=f2bf(f0[2]); hh[3]=f2bf(f0[3]);
        hh[4]=f2bf(f1[0]); hh[5]=f2bf(f1[1]); hh[6]=f2bf(f1[2]); hh[7]=f2bf(f1[3]);
        int idx = row * 8 + (k8 ^ (row & 7));
        *(u16x8*)&As[idx * 8] = hh;
      }
    } else if (ASRC == 2) {
      const float* A = (const float*)Ap;
      #pragma unroll
      for (int i = 0; i < 4; ++i) {
        int c = i * 256 + tid; int row = c >> 3, k8 = c & 7;
        int col0 = kt * 64 + k8 * 8;
        int h = col0 >> 5;
        size_t base = (size_t)(arow0 + row) * 256 + col0;
        f32x4 lo = {}, hi4 = {};
        float dsum = 0.f;
        #pragma unroll
        for (int ss = 0; ss < 4; ++ss) {
          const float* p = A + ss * 1048576;
          lo  += *(const f32x4*)(p + base);
          hi4 += *(const f32x4*)(p + base + 4);
          dsum += Dp[(ss * 4096 + arow0 + row) * 8 + h];
        }
        float inv = 1.0f / dsum;
        u16x8 hh;
        hh[0]=f2bf(lo[0]*inv);  hh[1]=f2bf(lo[1]*inv);  hh[2]=f2bf(lo[2]*inv);  hh[3]=f2bf(lo[3]*inv);
        hh[4]=f2bf(hi4[0]*inv); hh[5]=f2bf(hi4[1]*inv); hh[6]=f2bf(hi4[2]*inv); hh[7]=f2bf(hi4[3]*inv);
        int idx = row * 8 + (k8 ^ (row & 7));
        *(u16x8*)&As[idx * 8] = hh;
      }
    } else {
      const u16* A = (const u16*)Ap;
      #pragma unroll
      for (int i = 0; i < 4; ++i) {
        int c = i * 256 + tid; int row = c >> 3, seg = c & 7;
        const u16* src = A + (size_t)(arow0 + row) * K + kt * 64 + (seg ^ (row & 7)) * 8;
        glds16(src, (char*)As + (i * 256 + w * 64) * 16);
      }
    }
    // ---- stage B tile via global_load_lds, source pre-swizzled ----
    #pragma unroll
    for (int i = 0; i < 4; ++i) {
      int c = i * 256 + tid; int row = c >> 3, seg = c & 7;
      const u16* src = Bt + (size_t)(bcol0 + row) * K + kt * 64 + (seg ^ (row & 7)) * 8;
      glds16(src, (char*)Bs + (i * 256 + w * 64) * 16);
    }
    __syncthreads();
    // ---- compute ----
    #pragma unroll
    for (int kk = 0; kk < 2; ++kk) {
      bf16x8 af[4], bfr[4];
      #pragma unroll
      for (int mi = 0; mi < 4; ++mi) {
        int row = wr * 64 + mi * 16 + ln15;
        int idx = row * 8 + ((kk * 4 + g) ^ (row & 7));
        af[mi] = __builtin_bit_cast(bf16x8, *(const u32x4*)&As[idx * 8]);
      }
      #pragma unroll
      for (int ni = 0; ni < 4; ++ni) {
        int row = wc * 64 + ni * 16 + ln15;
        int idx = row * 8 + ((kk * 4 + g) ^ (row & 7));
        bfr[ni] = __builtin_bit_cast(bf16x8, *(const u32x4*)&Bs[idx * 8]);
      }
      #pragma unroll
      for (int mi = 0; mi < 4; ++mi)
        #pragma unroll
        for (int ni = 0; ni < 4; ++ni)
          acc[mi][ni] = __builtin_amdgcn_mfma_f32_16x16x32_bf16(af[mi], bfr[ni], acc[mi][ni], 0, 0, 0);
    }
  }
  // ---- epilogue ----
  #pragma unroll
  for (int mi = 0; mi < 4; ++mi) {
    #pragma unroll
    for (int ni = 0; ni < 4; ++ni) {
      int col = bcol0 + wc * 64 + ni * 16 + ln15;
      float bv = bias[col];
      #pragma unroll
      for (int r = 0; r < 4; ++r) {
        int row = arow0 + wr * 64 + mi * 16 + g * 4 + r;
        float v = acc[mi][ni][r] + bv;
        if (EPI == 0) {
          ((float*)Cp)[(size_t)row * N + col] = v;
        } else if (EPI == 1) {
          ((u16*)Cp)[(size_t)row * N + col] = f2bf(v * scale);
        } else {  // kv split; M=32768 = 8 batches x 4096
          int b = row >> 12, nk = row & 4095;
          if (col < 256) {
            int h = col >> 5, d = col & 31;
            ((u16*)Cp)[((size_t)((b << 3) + h) * 4096 + nk) * 32 + d] = f2bf(v);
          } else {
            int c2 = col - 256; int h = c2 >> 5, d = c2 & 31;
            ((u16*)C2p)[((size_t)((b << 3) + h) * 4096 + nk) * 32 + d] = f2bf(v);
          }
        }
      }
    }
  }
}

// q-GEMM merged into kv-GEMM launch: blocks [0,1024) = kv, [1024,1088) = q.
__global__ __launch_bounds__(256) void gemm12_k(const float* __restrict__ state,
                                                const float* __restrict__ pc,
                                                const u16* __restrict__ WqT,
                                                const u16* __restrict__ WkvT,
                                                const float* __restrict__ bq,
                                                const float* __restrict__ bkv,
                                                u16* __restrict__ qbuf, u16* __restrict__ kbuf,
                                                u16* __restrict__ vbuf, float qscl) {
  __shared__ __align__(16) u16 As[128 * 64];
  __shared__ __align__(16) u16 Bs[128 * 64];
  int bid = blockIdx.x;
  if (bid < 1024) {
    gemm_body<2, 1, true >(pc, WkvT, bkv, kbuf, vbuf, nullptr, As, Bs, 512, 256, 1.f, bid, 1024);
  } else {
    gemm_body<1, 1, false>(state, WqT, bq, qbuf, nullptr, nullptr, As, Bs, 256, 32, qscl, bid - 1024, 64);
  }
}

__global__ __launch_bounds__(256) void gemm3_k(const float* __restrict__ Op,
                                               const u16* __restrict__ WoT,
                                               const float* __restrict__ bo,
                                               float* __restrict__ out,
                                               const float* __restrict__ Dp) {
  __shared__ __align__(16) u16 As[128 * 64];
  __shared__ __align__(16) u16 Bs[128 * 64];
  gemm_body<0, 2, false>(Op, WoT, bo, out, nullptr, Dp, As, Bs, 256, 32, 1.f, blockIdx.x, 64);
}

// ---------------- fused attention: block = (qblk, bh, s) — one K-split stream ----------------
// 256 threads = 4 q-waves of 32 rows; keys [s*1024,(s+1)*1024) double-buffered in LDS.
// Swapped QK^T (32x32x16), in-register exp2, cvt_pk+permlane32_swap -> PV A-frags.
// Writes unnormalized O-partial (f32) + den-partial; gemm3 staging combines + normalizes.
__global__ __launch_bounds__(256) void attn_k(const u16* __restrict__ qb,
                                              const u16* __restrict__ kb,
                                              const u16* __restrict__ vb,
                                              float* __restrict__ Op,
                                              float* __restrict__ Dp) {
  __shared__ __align__(16) u16 Ks[2][2048];  // [buf][4 dchunk][64 krow][8]
  __shared__ __align__(16) u16 Vt[2][2048];  // [buf][32 d][64 k] chunk-swizzled
  int tid = threadIdx.x, lane = tid & 63, w = tid >> 6;
  int hi = lane >> 5, ln31 = lane & 31;
  int bid = blockIdx.x;
  int qblk = bid >> 8, r2 = bid & 255, bh = r2 >> 2, s = r2 & 3;  // qblk stride 256 => same XCD
  int b = bh >> 3, h = bh & 7;
  const u16* khead = kb + ((size_t)bh * 4096 + s * 1024) * 32;
  const u16* vhead = vb + ((size_t)bh * 4096 + s * 1024) * 32;
  int qrow0 = b * 512 + qblk * 128 + w * 32;

  // Q fragments (B-operand): n=q-col=lane&31, k'=d = ks*16 + hi*8 + j
  bf16x8 qf[2];
  #pragma unroll
  for (int ks = 0; ks < 2; ++ks) {
    const u16* src = qb + (size_t)(qrow0 + ln31) * 256 + h * 32 + ks * 16 + hi * 8;
    qf[ks] = __builtin_bit_cast(bf16x8, *(const u32x4*)src);
  }

  f32x16 O = {};
  float den = 0.f;
  int vrow = tid >> 2, vdc = tid & 3;

  auto loadV = [&](int t) -> u32x4 {
    return *(const u32x4*)(vhead + ((size_t)t * 64 + vrow) * 32 + vdc * 8);
  };
  auto stage = [&](int buf, int t, u32x4 vv) {
    // K: wave w stages d-chunk w (linear LDS dest, per-lane global src)
    glds16(khead + ((size_t)t * 64 + lane) * 32 + w * 8, (char*)&Ks[buf][0] + w * 1024);
    // V transpose into LDS: element (k=vrow, d=vdc*8+j); chunk swizzle c' = c ^ (d&7) ^ ((d>>3)<<1)
    u16x8 us = __builtin_bit_cast(u16x8, vv);
    #pragma unroll
    for (int j = 0; j < 8; ++j) {
      int d = vdc * 8 + j;
      int cs = (vrow >> 3) ^ j ^ (vdc << 1);
      Vt[buf][d * 64 + cs * 8 + (vrow & 7)] = us[j];
    }
  };

  u32x4 vv = loadV(0);
  stage(0, 0, vv);
  vv = loadV(1);
  __syncthreads();

  for (int t = 0; t < 16; ++t) {
    int buf = t & 1;
    if (t + 1 < 16) {
      stage(buf ^ 1, t + 1, vv);
      vv = loadV(t + 2 < 16 ? t + 2 : 15);
    }
    // ---- S^T = K * Q^T ----
    f32x16 sT[2] = {};
    #pragma unroll
    for (int ks = 0; ks < 2; ++ks) {
      #pragma unroll
      for (int mt = 0; mt < 2; ++mt) {
        const u16* ka = &Ks[buf][((ks * 2 + hi) * 64 + mt * 32 + ln31) * 8];
        bf16x8 kf = __builtin_bit_cast(bf16x8, *(const u32x4*)ka);
        sT[mt] = __builtin_amdgcn_mfma_f32_32x32x16_bf16(kf, qf[ks], sT[mt], 0, 0, 0);
      }
    }
    // ---- p = 2^s, den, pack to PV A-frags ----
    u32 pa[4][4];
    #pragma unroll
    for (int mt = 0; mt < 2; ++mt) {
      float p[16];
      #pragma unroll
      for (int r = 0; r < 16; ++r) p[r] = __builtin_amdgcn_exp2f(sT[mt][r]);
      #pragma unroll
      for (int r = 0; r < 16; ++r) den += p[r];
      u32 pk0[4], pk1[4];
      #pragma unroll
      for (int c = 0; c < 4; ++c) {
        asm("v_cvt_pk_bf16_f32 %0, %1, %2" : "=v"(pk0[c]) : "v"(p[4*c+0]), "v"(p[4*c+1]));
        asm("v_cvt_pk_bf16_f32 %0, %1, %2" : "=v"(pk1[c]) : "v"(p[4*c+2]), "v"(p[4*c+3]));
      }
      u32 a0 = pk0[0], b0 = pk0[1];
      asm("v_permlane32_swap_b32 %0, %1" : "+v"(a0), "+v"(b0));
      u32 a1 = pk1[0], b1 = pk1[1];
      asm("v_permlane32_swap_b32 %0, %1" : "+v"(a1), "+v"(b1));
      u32 a2 = pk0[2], b2 = pk0[3];
      asm("v_permlane32_swap_b32 %0, %1" : "+v"(a2), "+v"(b2));
      u32 a3 = pk1[2], b3 = pk1[3];
      asm("v_permlane32_swap_b32 %0, %1" : "+v"(a3), "+v"(b3));
      pa[mt*2+0][0] = a0; pa[mt*2+0][1] = a1; pa[mt*2+0][2] = b0; pa[mt*2+0][3] = b1;
      pa[mt*2+1][0] = a2; pa[mt*2+1][1] = a3; pa[mt*2+1][2] = b2; pa[mt*2+1][3] = b3;
    }
    // ---- O += P * V ----
    #pragma unroll
    for (int kst = 0; kst < 4; ++kst) {
      int cs = (kst * 2 + hi) ^ (ln31 & 7) ^ ((ln31 >> 3) << 1);
      const u16* va = &Vt[buf][ln31 * 64 + cs * 8];
      bf16x8 vf = __builtin_bit_cast(bf16x8, *(const u32x4*)va);
      u32x4 paw = {pa[kst][0], pa[kst][1], pa[kst][2], pa[kst][3]};
      O = __builtin_amdgcn_mfma_f32_32x32x16_bf16(__builtin_bit_cast(bf16x8, paw), vf, O, 0, 0, 0);
    }
    __syncthreads();
  }

  // ---- store unnormalized partials ----
  den += __shfl_xor(den, 32);
  float* op = Op + (size_t)s * 1048576;   // [s][4096][256] f32
  #pragma unroll
  for (int r = 0; r < 16; ++r) {
    int qr = 8 * (r >> 2) + 4 * hi + (r & 3);
    op[(size_t)(qrow0 + qr) * 256 + h * 32 + ln31] = O[r];
  }
  if (lane < 32) Dp[(size_t)(s * 4096 + qrow0 + ln31) * 8 + h] = den;
}

// ---------------- host ----------------
extern "C" void kernel_launch(void* const* d_in, const int* in_sizes, int n_in,
                              void* d_out, int out_size, void* d_ws, size_t ws_size,
                              hipStream_t stream) {
  const float* state = (const float*)d_in[0];
  const float* pc    = (const float*)d_in[1];
  const float* Wq    = (const float*)d_in[2];
  const float* bq    = (const float*)d_in[3];
  const float* Wkv   = (const float*)d_in[4];
  const float* bkv   = (const float*)d_in[5];
  const float* Wo    = (const float*)d_in[6];
  const float* bo    = (const float*)d_in[7];
  char* ws = (char*)d_ws;
  u16*   WqT  = (u16*)(ws);
  u16*   WkvT = (u16*)(ws + 131072);
  u16*   WoT  = (u16*)(ws + 393216);
  u16*   qb   = (u16*)(ws + 524288);      // [4096][256] bf16, pre-scaled by SCALE*log2e
  u16*   kb   = (u16*)(ws + 2621440);     // [64][4096][32] bf16
  u16*   vb   = (u16*)(ws + 19398656);    // [64][4096][32] bf16
  float* Op   = (float*)(ws + 36175872);  // [4][4096][256] f32 unnormalized O partials
  float* Dp   = (float*)(ws + 52953088);  // [4][4096][8] f32 den partials

  castw_k<<<1024, 256, 0, stream>>>(Wq, Wkv, Wo, WqT, WkvT, WoT);
  const float QSCL = 0.17677669529663687f * 1.4426950408889634f;  // SCALE * log2(e)
  gemm12_k<<<1088, 256, 0, stream>>>(state, pc, WqT, WkvT, bq, bkv, qb, kb, vb, QSCL);
  attn_k<<<1024, 256, 0, stream>>>(qb, kb, vb, Op, Dp);
  gemm3_k<<<64, 256, 0, stream>>>(Op, WoT, bo, (float*)d_out, Dp);
}

// Round 7
// 156.849 us; speedup vs baseline: 1.0923x; 1.0923x over previous
//
#include <hip/hip_runtime.h>

typedef unsigned short u16;
typedef unsigned int   u32;
typedef __bf16 bf16x8 __attribute__((ext_vector_type(8)));
typedef float  f32x4  __attribute__((ext_vector_type(4)));
typedef float  f32x16 __attribute__((ext_vector_type(16)));
typedef u32    u32x4  __attribute__((ext_vector_type(4)));
typedef u16    u16x8  __attribute__((ext_vector_type(8)));

#define DEVINL __device__ __forceinline__

DEVINL void glds16(const void* g, void* l) {
  __builtin_amdgcn_global_load_lds((const __attribute__((address_space(1))) u32*)g,
                                   (__attribute__((address_space(3))) u32*)l, 16, 0, 0);
}

DEVINL u16 f2bf(float f) {  // RNE float->bf16 (finite inputs)
  u32 u = __builtin_bit_cast(u32, f);
  u32 r = u + 0x7fffu + ((u >> 16) & 1u);
  return (u16)(r >> 16);
}

DEVINL u32 cvtpk(float lo, float hi) {  // packed f32x2 -> bf16x2 (RNE)
  u32 r;
  asm("v_cvt_pk_bf16_f32 %0, %1, %2" : "=v"(r) : "v"(lo), "v"(hi));
  return r;
}

DEVINL u16x8 cvt8(f32x4 a, f32x4 b) {
  u32x4 r = {cvtpk(a[0], a[1]), cvtpk(a[2], a[3]), cvtpk(b[0], b[1]), cvtpk(b[2], b[3])};
  return __builtin_bit_cast(u16x8, r);
}

// ---------------- prep: weight transpose-cast + activation cast ----------------
// blocks [0,1024): weights (262144 scalar elems — grid MUST cover all of them).
// blocks [1024,1536): state cast 4096x256 (131072 u16x8 units).
// blocks [1536,5632): pointcloud cast 32768x256 (1048576 units).
__global__ __launch_bounds__(256) void prep_k(const float* __restrict__ Wq,
                                              const float* __restrict__ Wkv,
                                              const float* __restrict__ Wo,
                                              const float* __restrict__ state,
                                              const float* __restrict__ pc,
                                              u16* __restrict__ WqT, u16* __restrict__ WkvT,
                                              u16* __restrict__ WoT, u16* __restrict__ sb,
                                              u16* __restrict__ pb) {
  int bid = blockIdx.x, tid = threadIdx.x;
  if (bid < 1024) {
    int i = bid * 256 + tid;
    if (i < 65536) {              // Wq 256x256
      int n = i >> 8, k = i & 255;
      WqT[i] = f2bf(Wq[k * 256 + n]);
    } else if (i < 196608) {      // Wkv 256x512
      int j = i - 65536; int n = j >> 8, k = j & 255;
      WkvT[j] = f2bf(Wkv[k * 512 + n]);
    } else {                      // Wo 256x256
      int j = i - 196608; int n = j >> 8, k = j & 255;
      WoT[j] = f2bf(Wo[k * 256 + n]);
    }
  } else if (bid < 1536) {
    size_t u = (size_t)(bid - 1024) * 256 + tid;
    f32x4 a = *(const f32x4*)(state + u * 8);
    f32x4 b = *(const f32x4*)(state + u * 8 + 4);
    *(u16x8*)(sb + u * 8) = cvt8(a, b);
  } else {
    size_t u = (size_t)(bid - 1536) * 256 + tid;
    f32x4 a = *(const f32x4*)(pc + u * 8);
    f32x4 b = *(const f32x4*)(pc + u * 8 + 4);
    *(u16x8*)(pb + u * 8) = cvt8(a, b);
  }
}

// ---------------- GEMM body: C[M][N] = A[M][256] * Bt[N][256]^T + bias ----------------
// All-bf16 A/B via global_load_lds, XOR-swizzled 16B chunks, double-buffered LDS,
// 2-phase K-loop: STAGE(next) || compute(cur), one barrier per step (T3-minimum).
// EPI 0: f32 out (+bias).  EPI 1: bf16 out, (acc+bias)*scale.  EPI 2: kv split per-head K/V.
// XCDSWZ: chunk blocks per XCD so nt-siblings of an A-panel share L2 (nblk%8==0).
template<int EPI, bool XCDSWZ>
DEVINL void gemm_body(const u16* __restrict__ A, const u16* __restrict__ Bt,
                      const float* __restrict__ bias, void* __restrict__ Cp,
                      void* __restrict__ C2p, u16* As, u16* Bs,
                      int N, int nmt, float scale, int bid, int nblk) {
  const int K = 256;
  int tid = threadIdx.x, lane = tid & 63, w = tid >> 6;
  int g = lane >> 4, ln15 = lane & 15;
  int mt, nt;
  if (XCDSWZ) {
    int u = (bid & 7) * (nblk >> 3) + (bid >> 3);  // contiguous chunk per XCD
    mt = u >> 2; nt = u & 3;                       // XCD covers all nt of its mt range
  } else {
    mt = bid % nmt; nt = bid / nmt;
  }
  int arow0 = mt * 128, bcol0 = nt * 128;
  int wr = w >> 1, wc = w & 1;
  f32x4 acc[4][4] = {};

  auto stage = [&](int buf, int kt) {
    #pragma unroll
    for (int i = 0; i < 4; ++i) {
      int c = i * 256 + tid; int row = c >> 3, seg = c & 7;
      glds16(A + (size_t)(arow0 + row) * K + kt * 64 + (seg ^ (row & 7)) * 8,
             (char*)As + (size_t)buf * 16384 + (i * 256 + w * 64) * 16);
      glds16(Bt + (size_t)(bcol0 + row) * K + kt * 64 + (seg ^ (row & 7)) * 8,
             (char*)Bs + (size_t)buf * 16384 + (i * 256 + w * 64) * 16);
    }
  };

  stage(0, 0);
  __syncthreads();
  for (int kt = 0; kt < 4; ++kt) {
    int buf = kt & 1;
    if (kt < 3) stage(buf ^ 1, kt + 1);
    const u16* Ab = As + buf * 8192;
    const u16* Bb = Bs + buf * 8192;
    #pragma unroll
    for (int kk = 0; kk < 2; ++kk) {
      bf16x8 af[4], bfr[4];
      #pragma unroll
      for (int mi = 0; mi < 4; ++mi) {
        int row = wr * 64 + mi * 16 + ln15;
        int idx = row * 8 + ((kk * 4 + g) ^ (row & 7));
        af[mi] = __builtin_bit_cast(bf16x8, *(const u32x4*)&Ab[idx * 8]);
      }
      #pragma unroll
      for (int ni = 0; ni < 4; ++ni) {
        int row = wc * 64 + ni * 16 + ln15;
        int idx = row * 8 + ((kk * 4 + g) ^ (row & 7));
        bfr[ni] = __builtin_bit_cast(bf16x8, *(const u32x4*)&Bb[idx * 8]);
      }
      #pragma unroll
      for (int mi = 0; mi < 4; ++mi)
        #pragma unroll
        for (int ni = 0; ni < 4; ++ni)
          acc[mi][ni] = __builtin_amdgcn_mfma_f32_16x16x32_bf16(af[mi], bfr[ni], acc[mi][ni], 0, 0, 0);
    }
    __syncthreads();   // drains next-tile glds16 (vmcnt0) + all waves done reading buf
  }
  // ---- epilogue ----
  #pragma unroll
  for (int mi = 0; mi < 4; ++mi) {
    #pragma unroll
    for (int ni = 0; ni < 4; ++ni) {
      int col = bcol0 + wc * 64 + ni * 16 + ln15;
      float bv = bias[col];
      #pragma unroll
      for (int r = 0; r < 4; ++r) {
        int row = arow0 + wr * 64 + mi * 16 + g * 4 + r;
        float v = acc[mi][ni][r] + bv;
        if (EPI == 0) {
          ((float*)Cp)[(size_t)row * N + col] = v;
        } else if (EPI == 1) {
          ((u16*)Cp)[(size_t)row * N + col] = f2bf(v * scale);
        } else {  // kv split; M=32768 = 8 batches x 4096
          int b = row >> 12, nk = row & 4095;
          if (col < 256) {
            int h = col >> 5, d = col & 31;
            ((u16*)Cp)[((size_t)((b << 3) + h) * 4096 + nk) * 32 + d] = f2bf(v);
          } else {
            int c2 = col - 256; int h = c2 >> 5, d = c2 & 31;
            ((u16*)C2p)[((size_t)((b << 3) + h) * 4096 + nk) * 32 + d] = f2bf(v);
          }
        }
      }
    }
  }
}

// q-GEMM merged into kv-GEMM launch: blocks [0,1024) = kv, [1024,1088) = q.
__global__ __launch_bounds__(256) void gemm12_k(const u16* __restrict__ sb,
                                                const u16* __restrict__ pb,
                                                const u16* __restrict__ WqT,
                                                const u16* __restrict__ WkvT,
                                                const float* __restrict__ bq,
                                                const float* __restrict__ bkv,
                                                u16* __restrict__ qbuf, u16* __restrict__ kbuf,
                                                u16* __restrict__ vbuf, float qscl) {
  __shared__ __align__(16) u16 As[2 * 8192];
  __shared__ __align__(16) u16 Bs[2 * 8192];
  int bid = blockIdx.x;
  if (bid < 1024) {
    gemm_body<2, true >(pb, WkvT, bkv, kbuf, vbuf, As, Bs, 512, 256, 1.f, bid, 1024);
  } else {
    gemm_body<1, false>(sb, WqT, bq, qbuf, nullptr, As, Bs, 256, 32, qscl, bid - 1024, 64);
  }
}

__global__ __launch_bounds__(256) void gemm3_k(const u16* __restrict__ ob,
                                               const u16* __restrict__ WoT,
                                               const float* __restrict__ bo,
                                               float* __restrict__ out) {
  __shared__ __align__(16) u16 As[2 * 8192];
  __shared__ __align__(16) u16 Bs[2 * 8192];
  gemm_body<0, false>(ob, WoT, bo, out, nullptr, As, Bs, 256, 32, 1.f, blockIdx.x, 64);
}

// ---------------- reduce: sum 4 O-partials, normalize by summed den, cast bf16 ----------------
// 512 blocks x 256 thr, one u16x8 unit each: u in [0,131072), row=u>>5, col0=(u&31)*8.
__global__ __launch_bounds__(256) void reduce_k(const float* __restrict__ Op,
                                                const float* __restrict__ Dp,
                                                u16* __restrict__ ob) {
  size_t u = (size_t)blockIdx.x * 256 + threadIdx.x;
  int row = (int)(u >> 5), q8 = (int)(u & 31);
  int h = q8 >> 2;
  size_t base = u * 8;
  f32x4 lo = {}, hi = {};
  float dsum = 0.f;
  #pragma unroll
  for (int ss = 0; ss < 4; ++ss) {
    const float* p = Op + (size_t)ss * 1048576;
    lo += *(const f32x4*)(p + base);
    hi += *(const f32x4*)(p + base + 4);
    dsum += Dp[((size_t)ss * 4096 + row) * 8 + h];
  }
  float inv = 1.0f / dsum;
  lo *= inv; hi *= inv;
  *(u16x8*)(ob + base) = cvt8(lo, hi);
}

// ---------------- fused attention: block = (qblk, bh, s) — one K-split stream ----------------
// 256 threads = 4 q-waves of 32 rows; keys [s*1024,(s+1)*1024) double-buffered in LDS.
// Swapped QK^T (32x32x16), in-register exp2, cvt_pk+permlane32_swap -> PV A-frags.
// Writes unnormalized O-partial (f32) + den-partial; reduce_k combines + normalizes.
__global__ __launch_bounds__(256) void attn_k(const u16* __restrict__ qb,
                                              const u16* __restrict__ kb,
                                              const u16* __restrict__ vb,
                                              float* __restrict__ Op,
                                              float* __restrict__ Dp) {
  __shared__ __align__(16) u16 Ks[2][2048];  // [buf][4 dchunk][64 krow][8]
  __shared__ __align__(16) u16 Vt[2][2048];  // [buf][32 d][64 k] chunk-swizzled
  int tid = threadIdx.x, lane = tid & 63, w = tid >> 6;
  int hi = lane >> 5, ln31 = lane & 31;
  int bid = blockIdx.x;
  int qblk = bid >> 8, r2 = bid & 255, bh = r2 >> 2, s = r2 & 3;  // qblk stride 256 => same XCD
  int b = bh >> 3, h = bh & 7;
  const u16* khead = kb + ((size_t)bh * 4096 + s * 1024) * 32;
  const u16* vhead = vb + ((size_t)bh * 4096 + s * 1024) * 32;
  int qrow0 = b * 512 + qblk * 128 + w * 32;

  // Q fragments (B-operand): n=q-col=lane&31, k'=d = ks*16 + hi*8 + j
  bf16x8 qf[2];
  #pragma unroll
  for (int ks = 0; ks < 2; ++ks) {
    const u16* src = qb + (size_t)(qrow0 + ln31) * 256 + h * 32 + ks * 16 + hi * 8;
    qf[ks] = __builtin_bit_cast(bf16x8, *(const u32x4*)src);
  }

  f32x16 O = {};
  float den = 0.f;
  int vrow = tid >> 2, vdc = tid & 3;

  auto loadV = [&](int t) -> u32x4 {
    return *(const u32x4*)(vhead + ((size_t)t * 64 + vrow) * 32 + vdc * 8);
  };
  auto stage = [&](int buf, int t, u32x4 vv) {
    // K: wave w stages d-chunk w (linear LDS dest, per-lane global src)
    glds16(khead + ((size_t)t * 64 + lane) * 32 + w * 8, (char*)&Ks[buf][0] + w * 1024);
    // V transpose into LDS: element (k=vrow, d=vdc*8+j); chunk swizzle c' = c ^ (d&7) ^ ((d>>3)<<1)
    u16x8 us = __builtin_bit_cast(u16x8, vv);
    #pragma unroll
    for (int j = 0; j < 8; ++j) {
      int d = vdc * 8 + j;
      int cs = (vrow >> 3) ^ j ^ (vdc << 1);
      Vt[buf][d * 64 + cs * 8 + (vrow & 7)] = us[j];
    }
  };

  u32x4 vv = loadV(0);
  stage(0, 0, vv);
  vv = loadV(1);
  __syncthreads();

  for (int t = 0; t < 16; ++t) {
    int buf = t & 1;
    if (t + 1 < 16) {
      stage(buf ^ 1, t + 1, vv);
      vv = loadV(t + 2 < 16 ? t + 2 : 15);
    }
    // ---- S^T = K * Q^T ----
    f32x16 sT[2] = {};
    #pragma unroll
    for (int ks = 0; ks < 2; ++ks) {
      #pragma unroll
      for (int mt = 0; mt < 2; ++mt) {
        const u16* ka = &Ks[buf][((ks * 2 + hi) * 64 + mt * 32 + ln31) * 8];
        bf16x8 kf = __builtin_bit_cast(bf16x8, *(const u32x4*)ka);
        sT[mt] = __builtin_amdgcn_mfma_f32_32x32x16_bf16(kf, qf[ks], sT[mt], 0, 0, 0);
      }
    }
    // ---- p = 2^s, den, pack to PV A-frags ----
    u32 pa[4][4];
    #pragma unroll
    for (int mt = 0; mt < 2; ++mt) {
      float p[16];
      #pragma unroll
      for (int r = 0; r < 16; ++r) p[r] = __builtin_amdgcn_exp2f(sT[mt][r]);
      #pragma unroll
      for (int r = 0; r < 16; ++r) den += p[r];
      u32 pk0[4], pk1[4];
      #pragma unroll
      for (int c = 0; c < 4; ++c) {
        pk0[c] = cvtpk(p[4*c+0], p[4*c+1]);
        pk1[c] = cvtpk(p[4*c+2], p[4*c+3]);
      }
      u32 a0 = pk0[0], b0 = pk0[1];
      asm("v_permlane32_swap_b32 %0, %1" : "+v"(a0), "+v"(b0));
      u32 a1 = pk1[0], b1 = pk1[1];
      asm("v_permlane32_swap_b32 %0, %1" : "+v"(a1), "+v"(b1));
      u32 a2 = pk0[2], b2 = pk0[3];
      asm("v_permlane32_swap_b32 %0, %1" : "+v"(a2), "+v"(b2));
      u32 a3 = pk1[2], b3 = pk1[3];
      asm("v_permlane32_swap_b32 %0, %1" : "+v"(a3), "+v"(b3));
      pa[mt*2+0][0] = a0; pa[mt*2+0][1] = a1; pa[mt*2+0][2] = b0; pa[mt*2+0][3] = b1;
      pa[mt*2+1][0] = a2; pa[mt*2+1][1] = a3; pa[mt*2+1][2] = b2; pa[mt*2+1][3] = b3;
    }
    // ---- O += P * V ----
    #pragma unroll
    for (int kst = 0; kst < 4; ++kst) {
      int cs = (kst * 2 + hi) ^ (ln31 & 7) ^ ((ln31 >> 3) << 1);
      const u16* va = &Vt[buf][ln31 * 64 + cs * 8];
      bf16x8 vf = __builtin_bit_cast(bf16x8, *(const u32x4*)va);
      u32x4 paw = {pa[kst][0], pa[kst][1], pa[kst][2], pa[kst][3]};
      O = __builtin_amdgcn_mfma_f32_32x32x16_bf16(__builtin_bit_cast(bf16x8, paw), vf, O, 0, 0, 0);
    }
    __syncthreads();
  }

  // ---- store unnormalized partials ----
  den += __shfl_xor(den, 32);
  float* op = Op + (size_t)s * 1048576;   // [s][4096][256] f32
  #pragma unroll
  for (int r = 0; r < 16; ++r) {
    int qr = 8 * (r >> 2) + 4 * hi + (r & 3);
    op[(size_t)(qrow0 + qr) * 256 + h * 32 + ln31] = O[r];
  }
  if (lane < 32) Dp[(size_t)(s * 4096 + qrow0 + ln31) * 8 + h] = den;
}

// ---------------- host ----------------
extern "C" void kernel_launch(void* const* d_in, const int* in_sizes, int n_in,
                              void* d_out, int out_size, void* d_ws, size_t ws_size,
                              hipStream_t stream) {
  const float* state = (const float*)d_in[0];
  const float* pc    = (const float*)d_in[1];
  const float* Wq    = (const float*)d_in[2];
  const float* bq    = (const float*)d_in[3];
  const float* Wkv   = (const float*)d_in[4];
  const float* bkv   = (const float*)d_in[5];
  const float* Wo    = (const float*)d_in[6];
  const float* bo    = (const float*)d_in[7];
  char* ws = (char*)d_ws;
  u16*   WqT  = (u16*)(ws);                // 128 KB
  u16*   WkvT = (u16*)(ws + 131072);       // 256 KB
  u16*   WoT  = (u16*)(ws + 393216);       // 128 KB
  u16*   sb   = (u16*)(ws + 524288);       // [4096][256] bf16 state
  u16*   pb   = (u16*)(ws + 2621440);      // [32768][256] bf16 pointcloud
  u16*   qb   = (u16*)(ws + 19398656);     // [4096][256] bf16, pre-scaled
  u16*   kb   = (u16*)(ws + 21495808);     // [64][4096][32] bf16
  u16*   vb   = (u16*)(ws + 38273024);     // [64][4096][32] bf16
  u16*   ob   = (u16*)(ws + 55050240);     // [4096][256] bf16 attnout
  float* Op   = (float*)(ws + 57147392);   // [4][4096][256] f32 O partials
  float* Dp   = (float*)(ws + 73924608);   // [4][4096][8] f32 den partials

  prep_k<<<5632, 256, 0, stream>>>(Wq, Wkv, Wo, state, pc, WqT, WkvT, WoT, sb, pb);
  const float QSCL = 0.17677669529663687f * 1.4426950408889634f;  // SCALE * log2(e)
  gemm12_k<<<1088, 256, 0, stream>>>(sb, pb, WqT, WkvT, bq, bkv, qb, kb, vb, QSCL);
  attn_k<<<1024, 256, 0, stream>>>(qb, kb, vb, Op, Dp);
  reduce_k<<<512, 256, 0, stream>>>(Op, Dp, ob);
  gemm3_k<<<64, 256, 0, stream>>>(ob, WoT, bo, (float*)d_out);
}